// Round 8
// baseline (95.564 us; speedup 1.0000x reference)
//
#include <hip/hip_runtime.h>
#include <hip/hip_bf16.h>

typedef short bf16x8 __attribute__((ext_vector_type(8)));
typedef float f32x16 __attribute__((ext_vector_type(16)));
typedef float f4    __attribute__((ext_vector_type(4)));
typedef unsigned short u16;

#define D_DIM  128
#define S_LEN  16384
#define NBLK   512
#define NTILES 2048      // 262144 rows / 128 rows per block-tile (4 waves x 32 rows)
#define ITERS  4         // NTILES / NBLK

__device__ __forceinline__ u16 f2bf(float f) {
    __hip_bfloat16 h = __float2bfloat16(f);
    return __builtin_bit_cast(u16, h);
}

__launch_bounds__(256, 2)
__global__ void ssm_v8(const float* __restrict__ x,
                       const int*   __restrict__ mask,
                       const float* __restrict__ W1,
                       const float* __restrict__ b1,
                       const float* __restrict__ W2,
                       const float* __restrict__ b2,
                       float* __restrict__ out) {
    // 32 (W1) + 32 (W2) + 16 (h halves) = 80 KiB -> 2 blocks/CU, 8 waves/CU
    __shared__ __align__(16) u16 w1t[128*128];
    __shared__ __align__(16) u16 w2t[128*128];
    __shared__ __align__(16) u16 hlds[4*32*64];   // per-wave 32x64 u16 = 4 KiB

    const int tid = threadIdx.x;
    const int c   = tid & 31;          // MFMA row/col lane index (32-wide)
    const int g2  = (tid >> 5) & 1;    // k-group
    const int wv  = tid >> 6;

    // ---- stage W1^T, W2^T as bf16, [col][k] with XOR swizzle ----
    // W1 read sel = (col>>1)&7 (cols stride 2 in lanes); W2 sel = (col>>2)&7 (stride 4)
    for (int i = tid; i < 4096; i += 256) {
        int k  = i >> 5;
        int n0 = (i & 31) * 4;
        f4 v1 = *(const f4*)(W1 + k*128 + n0);
        f4 v2 = *(const f4*)(W2 + k*128 + n0);
#pragma unroll
        for (int j = 0; j < 4; ++j) {
            int col = n0 + j;
            w1t[(col*128 + k) ^ (((col >> 1) & 7) << 3)] = f2bf(v1[j]);
            w2t[(col*128 + k) ^ (((col >> 2) & 7) << 3)] = f2bf(v2[j]);
        }
    }
    __syncthreads();

    // per-lane bias frags at permuted columns
    float b1f[2][2], b2f[4];
#pragma unroll
    for (int p = 0; p < 2; ++p)
#pragma unroll
        for (int t = 0; t < 2; ++t)
            b1f[p][t] = b1[p*64 + 2*c + t];
#pragma unroll
    for (int t = 0; t < 4; ++t) b2f[t] = b2[4*c + t];

    u16* hw = hlds + wv * 2048;

    // ---- prologue prefetch: this wave's 32x128 x-slice + mask ----
    f4 stg[16];
    int4 mm[4];
    {
        const int row0w = blockIdx.x*128 + wv*32;
        const float* xp = x + (long)(row0w + c)*D_DIM + g2*8;
#pragma unroll
        for (int kc = 0; kc < 8; ++kc) {
            stg[2*kc]   = *(const f4*)(xp + kc*16);
            stg[2*kc+1] = *(const f4*)(xp + kc*16 + 4);
        }
#pragma unroll
        for (int q = 0; q < 4; ++q)
            mm[q] = *(const int4*)(mask + row0w + 8*q + 4*g2);
    }
    __builtin_amdgcn_sched_barrier(0);

#pragma unroll 1
    for (int it = 0; it < ITERS; ++it) {
        const int tile  = blockIdx.x + it*NBLK;
        const int row0w = tile*128 + wv*32;

        // ---- convert staged x -> bf16 A-frags (A row = lane&31, k = g2*8 + kc*16 + j) ----
        bf16x8 a[8];
#pragma unroll
        for (int kc = 0; kc < 8; ++kc) {
            const f4 lo = stg[2*kc], hi = stg[2*kc+1];
            bf16x8 t;
            t[0]=(short)f2bf(lo[0]); t[1]=(short)f2bf(lo[1]); t[2]=(short)f2bf(lo[2]); t[3]=(short)f2bf(lo[3]);
            t[4]=(short)f2bf(hi[0]); t[5]=(short)f2bf(hi[1]); t[6]=(short)f2bf(hi[2]); t[7]=(short)f2bf(hi[3]);
            a[kc] = t;
        }

        // ---- mask*decay factors (consume mm before refill) ----
        float mfac[16];
#pragma unroll
        for (int reg = 0; reg < 16; ++reg) {
            const int q = reg >> 2, s = reg & 3;
            const int mv  = ((const int*)&mm[q])[s];
            const int row = s + 8*q + 4*g2;
            const unsigned fr = (unsigned)((row0w + row) & (S_LEN - 1));
            const float sc = (((fr + 1u) % 10u) == 0u) ? 0.1f : 1.0f;
            mfac[reg] = mv ? sc : 0.0f;
        }

        // ---- refill staging for next tile (in flight through whole compute) ----
        if (it != ITERS - 1) {
            const int r0n = (tile + NBLK)*128 + wv*32;
            const float* xp = x + (long)(r0n + c)*D_DIM + g2*8;
#pragma unroll
            for (int kc = 0; kc < 8; ++kc) {
                stg[2*kc]   = *(const f4*)(xp + kc*16);
                stg[2*kc+1] = *(const f4*)(xp + kc*16 + 4);
            }
#pragma unroll
            for (int q = 0; q < 4; ++q)
                mm[q] = *(const int4*)(mask + r0n + 8*q + 4*g2);
        }
        __builtin_amdgcn_sched_barrier(0);

        f32x16 acc2[4] = {};

        // ---- two half-phases: L1 (64 cols) -> silu -> h-half -> L2 partial K ----
#pragma unroll
        for (int p = 0; p < 2; ++p) {
            f32x16 acc1[2] = {};
#pragma unroll
            for (int kc = 0; kc < 8; ++kc) {
                const int ko = kc*16 + g2*8;
#pragma unroll
                for (int t = 0; t < 2; ++t) {
                    const int col = p*64 + 2*c + t;     // true W1 col
                    const bf16x8 wb = *(const bf16x8*)&w1t[(col*128 + ko) ^ ((c & 7) << 3)];
                    acc1[t] = __builtin_amdgcn_mfma_f32_32x32x16_bf16(a[kc], wb, acc1[t], 0, 0, 0);
                }
            }
            // bias + silu -> packed ushort2 writes into 32x64 h-half (XOR-swizzled)
#pragma unroll
            for (int reg = 0; reg < 16; ++reg) {
                const int row = (reg & 3) + 8*(reg >> 2) + 4*g2;   // C/D row mapping (m74/m101)
                float z0 = acc1[0][reg] + b1f[p][0];
                float z1 = acc1[1][reg] + b1f[p][1];
                ushort2 pk;
                pk.x = f2bf(z0 / (1.f + __expf(-z0)));
                pk.y = f2bf(z1 / (1.f + __expf(-z1)));
                *(ushort2*)&hw[(row*64 + 2*c) ^ ((row & 7) << 3)] = pk;
            }
            // L2 partial: k in [p*64, p*64+64)
#pragma unroll
            for (int kc2 = 0; kc2 < 4; ++kc2) {
                const bf16x8 ha = *(const bf16x8*)&hw[(c*64 + kc2*16 + g2*8) ^ ((c & 7) << 3)];
                const int ko = p*64 + kc2*16 + g2*8;
#pragma unroll
                for (int t2 = 0; t2 < 4; ++t2) {
                    const int col = 4*c + t2;          // true W2 col
                    const bf16x8 wb = *(const bf16x8*)&w2t[(col*128 + ko) ^ ((c & 7) << 3)];
                    acc2[t2] = __builtin_amdgcn_mfma_f32_32x32x16_bf16(ha, wb, acc2[t2], 0, 0, 0);
                }
            }
        }

        // ---- epilogue: bias + mask/decay; line-complete f4 stores (32 lanes = full 512B row) ----
#pragma unroll
        for (int reg = 0; reg < 16; ++reg) {
            const int row = (reg & 3) + 8*(reg >> 2) + 4*g2;
            f4 f;
#pragma unroll
            for (int t2 = 0; t2 < 4; ++t2)
                f[t2] = (acc2[t2][reg] + b2f[t2]) * mfac[reg];
            *(f4*)(out + (long)(row0w + row)*D_DIM + 4*c) = f;
        }
    }
}

extern "C" void kernel_launch(void* const* d_in, const int* in_sizes, int n_in,
                              void* d_out, int out_size, void* d_ws, size_t ws_size,
                              hipStream_t stream) {
    const float* x    = (const float*)d_in[0];
    const int*   mask = (const int*)d_in[1];
    const float* W1   = (const float*)d_in[2];
    const float* b1   = (const float*)d_in[3];
    const float* W2   = (const float*)d_in[4];
    const float* b2   = (const float*)d_in[5];
    float* out = (float*)d_out;

    hipLaunchKernelGGL(ssm_v8, dim3(NBLK), dim3(256), 0, stream,
                       x, mask, W1, b1, W2, b2, out);
}